// Round 1
// baseline (292.438 us; speedup 1.0000x reference)
//
#include <hip/hip_runtime.h>
#include <math.h>

#define B 8
#define T 4096
#define D 512
#define NPAIR ((B * D) / 2)   // 2048 signal pairs
#define TOPK 7                // int(log(2047)) = 7
#define LOG2T 12

// ---------------------------------------------------------------------------
// Kernel 1: transpose + pack. x (B,T,D) f32 -> xp (B, D/2, T) float2
// xp[b][p][t] = (x[b][t][2p], x[b][t][2p+1])
// ---------------------------------------------------------------------------
__global__ __launch_bounds__(256) void k_transpose_pack(const float* __restrict__ x,
                                                        float2* __restrict__ xp) {
  __shared__ float tile[64][65];   // [t][d], pad to kill bank conflicts
  const int b  = blockIdx.z;
  const int t0 = blockIdx.x * 64;
  const int d0 = blockIdx.y * 64;
  const int tx = threadIdx.x;      // 0..63
  const int ty = threadIdx.y;      // 0..3

  for (int r = ty; r < 64; r += 4)
    tile[r][tx] = x[((size_t)b * T + (t0 + r)) * D + (d0 + tx)];
  __syncthreads();
  for (int rp = ty; rp < 32; rp += 4) {
    float2 v = make_float2(tile[tx][2 * rp], tile[tx][2 * rp + 1]);
    xp[((size_t)b * (D / 2) + (d0 / 2 + rp)) * T + (t0 + tx)] = v;
  }
}

// ---------------------------------------------------------------------------
// Kernel 3: unpack + transpose back. wt (B, D/2, T) float2 -> out (B,T,D) f32
// ---------------------------------------------------------------------------
__global__ __launch_bounds__(256) void k_transpose_unpack(const float2* __restrict__ wt,
                                                          float* __restrict__ out) {
  __shared__ float tile[64][65];   // [d][t]
  const int b  = blockIdx.z;
  const int t0 = blockIdx.x * 64;
  const int d0 = blockIdx.y * 64;
  const int tx = threadIdx.x;
  const int ty = threadIdx.y;

  for (int rp = ty; rp < 32; rp += 4) {
    float2 v = wt[((size_t)b * (D / 2) + (d0 / 2 + rp)) * T + (t0 + tx)];
    tile[2 * rp][tx]     = v.x;
    tile[2 * rp + 1][tx] = v.y;
  }
  __syncthreads();
  for (int r = ty; r < 64; r += 4)
    out[((size_t)b * T + (t0 + r)) * D + (d0 + tx)] = tile[tx][r];
}

// ---------------------------------------------------------------------------
// Radix-2 DIT FFT, bit-reversed input -> natural output, in LDS.
// sign = -1 forward (numpy rfft convention e^{-i}), +1 inverse (unnormalized).
// ---------------------------------------------------------------------------
__device__ inline void fft_stages(float2* Z, int tid, float sign) {
  for (int s = 1; s <= LOG2T; ++s) {
    const int mh = 1 << (s - 1);
    const float angScale = sign * (float)M_PI / (float)mh;
    for (int i = tid; i < T / 2; i += 256) {
      const int pos = i & (mh - 1);
      const int i0  = ((i >> (s - 1)) << s) | pos;
      const int i1  = i0 + mh;
      float c, sn;
      __sincosf(angScale * (float)pos, &sn, &c);
      const float2 a = Z[i0];
      const float2 b = Z[i1];
      const float tr = b.x * c - b.y * sn;
      const float ti = b.x * sn + b.y * c;
      Z[i0] = make_float2(a.x + tr, a.y + ti);
      Z[i1] = make_float2(a.x - tr, a.y - ti);
    }
    __syncthreads();
  }
}

// ---------------------------------------------------------------------------
// Kernel 2: per signal-pair: FFT -> top-7 per real signal -> sparse Hermitian
// spectrum (packed S1 + i*S2) -> inverse FFT -> time domain (in-place in xp).
// ---------------------------------------------------------------------------
__global__ __launch_bounds__(256) void k_fft_topk_ifft(float2* __restrict__ xp) {
  __shared__ float2 Z[T];            // 32 KB
  __shared__ float  amp[2][T / 2];   // 16 KB, squared amplitudes, k in 1..2047
  __shared__ float  s_val[256];
  __shared__ int    s_idx[256];
  __shared__ int    s_sel[2][TOPK];
  __shared__ float2 s_X[2 * TOPK];

  const int tid = threadIdx.x;
  float2* g = xp + (size_t)blockIdx.x * T;

  // load with bit-reversal (coalesced global read, scattered LDS write)
  for (int t = tid; t < T; t += 256) {
    const int rpos = __brev((unsigned)t) >> (32 - LOG2T);
    Z[rpos] = g[t];
  }
  __syncthreads();

  // forward FFT: Z[k] = X1[k] + i*X2[k]
  fft_stages(Z, tid, -1.0f);

  // unpack squared amplitudes of both real signals, bins 1..2047
  for (int k = 1 + tid; k < T / 2; k += 256) {
    const float2 zk = Z[k];
    const float2 zn = Z[T - k];
    const float x1r = 0.5f * (zk.x + zn.x), x1i = 0.5f * (zk.y - zn.y);
    const float x2r = 0.5f * (zk.y + zn.y), x2i = 0.5f * (zn.x - zk.x);
    amp[0][k] = x1r * x1r + x1i * x1i;
    amp[1][k] = x2r * x2r + x2i * x2i;
  }
  __syncthreads();

  // top-7 per signal: 7 sequential argmax reductions each
  for (int sh = 0; sh < 2; ++sh) {
    for (int it = 0; it < TOPK; ++it) {
      float bv = -1.0f;
      int   bi = 1;
      for (int k = 1 + tid; k < T / 2; k += 256) {
        const float v = amp[sh][k];
        if (v > bv) { bv = v; bi = k; }
      }
      s_val[tid] = bv;
      s_idx[tid] = bi;
      __syncthreads();
      for (int off = 128; off > 0; off >>= 1) {
        if (tid < off) {
          if (s_val[tid + off] > s_val[tid]) {
            s_val[tid] = s_val[tid + off];
            s_idx[tid] = s_idx[tid + off];
          }
        }
        __syncthreads();
      }
      if (tid == 0) {
        const int k = s_idx[0];
        s_sel[sh][it] = k;
        amp[sh][k] = -2.0f;   // exclude from later iterations
      }
      __syncthreads();
    }
  }

  // gather selected complex values (before zeroing Z)
  if (tid < 2 * TOPK) {
    const int sh = tid / TOPK;
    const int k  = s_sel[sh][tid % TOPK];
    const float2 zk = Z[k];
    const float2 zn = Z[T - k];
    float2 X;
    if (sh == 0) X = make_float2(0.5f * (zk.x + zn.x), 0.5f * (zk.y - zn.y));
    else         X = make_float2(0.5f * (zk.y + zn.y), 0.5f * (zn.x - zk.x));
    s_X[tid] = X;
  }
  __syncthreads();

  // zero spectrum
  for (int t = tid; t < T; t += 256) Z[t] = make_float2(0.0f, 0.0f);
  __syncthreads();

  // scatter sparse Hermitian spectrum, packed W = S1 + i*S2 (serial: 28 updates)
  if (tid == 0) {
    for (int j = 0; j < TOPK; ++j) {
      const int k = s_sel[0][j];
      const float2 X = s_X[j];
      Z[k].x     += X.x;  Z[k].y     += X.y;     // X1 at k
      Z[T - k].x += X.x;  Z[T - k].y += -X.y;    // conj(X1) at N-k
    }
    for (int j = 0; j < TOPK; ++j) {
      const int k = s_sel[1][j];
      const float2 X = s_X[TOPK + j];
      Z[k].x     += -X.y; Z[k].y     += X.x;     // i*X2 at k
      Z[T - k].x += X.y;  Z[T - k].y += X.x;     // i*conj(X2) at N-k
    }
  }
  __syncthreads();

  // bit-reverse permute in place
  for (int t = tid; t < T; t += 256) {
    const int r = __brev((unsigned)t) >> (32 - LOG2T);
    if (r > t) { const float2 tmp = Z[t]; Z[t] = Z[r]; Z[r] = tmp; }
  }
  __syncthreads();

  // inverse FFT (unnormalized): z[t] = s1[t] + i*s2[t]
  fft_stages(Z, tid, +1.0f);

  // write time-domain pair back (in-place is safe: own block's range only)
  for (int t = tid; t < T; t += 256) g[t] = Z[t];
}

// ---------------------------------------------------------------------------
extern "C" void kernel_launch(void* const* d_in, const int* in_sizes, int n_in,
                              void* d_out, int out_size, void* d_ws, size_t ws_size,
                              hipStream_t stream) {
  const float* x = (const float*)d_in[0];
  float* out = (float*)d_out;
  float2* xp = (float2*)d_ws;   // 64 MB: (B, D/2, T) float2, reused for time domain

  dim3 tgrid(T / 64, D / 64, B);
  dim3 tblock(64, 4, 1);
  hipLaunchKernelGGL(k_transpose_pack, tgrid, tblock, 0, stream, x, xp);
  hipLaunchKernelGGL(k_fft_topk_ifft, dim3(NPAIR), dim3(256), 0, stream, xp);
  hipLaunchKernelGGL(k_transpose_unpack, tgrid, tblock, 0, stream, xp, out);
}

// Round 2
// 202.523 us; speedup vs baseline: 1.4440x; 1.4440x over previous
//
#include <hip/hip_runtime.h>
#include <math.h>

#define B 8
#define T 4096
#define D 512
#define NPAIR ((B * D) / 2)   // 2048 signal pairs
#define TOPK 7                // int(log(2047)) = 7
#define LOG2T 12
#define PAD(e) ((e) + ((e) >> 4))
#define ZSZ (T + (T >> 4))

__device__ __forceinline__ int brev12(int x) {
  return (int)(__brev((unsigned)x) >> (32 - LOG2T));
}

// ---------------------------------------------------------------------------
// Kernel 1: transpose + pack. x (B,T,D) f32 -> xp (B, D/2, T) float2
// ---------------------------------------------------------------------------
__global__ __launch_bounds__(256) void k_transpose_pack(const float* __restrict__ x,
                                                        float2* __restrict__ xp) {
  __shared__ float tile[64][65];
  const int b  = blockIdx.z;
  const int t0 = blockIdx.x * 64;
  const int d0 = blockIdx.y * 64;
  const int tx = threadIdx.x;      // 0..63
  const int ty = threadIdx.y;      // 0..3

  for (int r = ty; r < 64; r += 4)
    tile[r][tx] = x[((size_t)b * T + (t0 + r)) * D + (d0 + tx)];
  __syncthreads();
  for (int rp = ty; rp < 32; rp += 4) {
    float2 v = make_float2(tile[tx][2 * rp], tile[tx][2 * rp + 1]);
    xp[((size_t)b * (D / 2) + (d0 / 2 + rp)) * T + (t0 + tx)] = v;
  }
}

// ---------------------------------------------------------------------------
// Kernel 2: forward FFT (radix-4 DIF, natural in -> bit-reversed out),
// register-resident amplitudes, top-7 per real signal, write 14 coeff float4s
// into this block's own (already consumed) xp region.
// ---------------------------------------------------------------------------
__global__ __launch_bounds__(256) void k_fft_topk(float2* __restrict__ xp) {
  __shared__ float2 Z[ZSZ];          // ~34 KB, padded
  __shared__ float  s_rv[4];
  __shared__ int    s_rk[4];
  __shared__ float4 s_cf[2 * TOPK];

  const int tid = threadIdx.x;
  float2* g = xp + (size_t)blockIdx.x * T;

  // coalesced natural-order load (DIF needs no input permutation)
  for (int t = tid; t < T; t += 256) Z[PAD(t)] = g[t];
  __syncthreads();

  // 6 fused radix-4 passes == 12 radix-2 DIF stages, forward (e^{-i...})
  for (int s = 0; s < 6; ++s) {
    const int shift = 10 - 2 * s;
    const int q = 1 << shift;
    const float ang_scale = -6.283185307179586f / (float)(q << 2);
    for (int i = tid; i < T / 4; i += 256) {
      const int p    = i & (q - 1);
      const int base = ((i >> shift) << (shift + 2)) | p;
      float2 a0 = Z[PAD(base)];
      float2 a1 = Z[PAD(base + q)];
      float2 a2 = Z[PAD(base + 2 * q)];
      float2 a3 = Z[PAD(base + 3 * q)];
      float sw, cw;
      __sincosf(ang_scale * (float)p, &sw, &cw);
      const float c2 = cw * cw - sw * sw, s2 = 2.0f * cw * sw;      // W^2
      const float c3 = c2 * cw - s2 * sw, s3 = c2 * sw + s2 * cw;   // W^3
      const float t0r = a0.x + a2.x, t0i = a0.y + a2.y;
      const float t1r = a0.x - a2.x, t1i = a0.y - a2.y;
      const float t2r = a1.x + a3.x, t2i = a1.y + a3.y;
      const float t3r = a1.x - a3.x, t3i = a1.y - a3.y;
      // y0 = t0 + t2
      Z[PAD(base)] = make_float2(t0r + t2r, t0i + t2i);
      // y1 = (t0 - t2) * W^2
      const float u1r = t0r - t2r, u1i = t0i - t2i;
      Z[PAD(base + q)] = make_float2(u1r * c2 - u1i * s2, u1r * s2 + u1i * c2);
      // y2 = (t1 - i*t3) * W
      const float u2r = t1r + t3i, u2i = t1i - t3r;
      Z[PAD(base + 2 * q)] = make_float2(u2r * cw - u2i * sw, u2r * sw + u2i * cw);
      // y3 = (t1 + i*t3) * W^3
      const float u3r = t1r - t3i, u3i = t1i + t3r;
      Z[PAD(base + 3 * q)] = make_float2(u3r * c3 - u3i * s3, u3r * s3 + u3i * c3);
    }
    __syncthreads();
  }

  // register-resident squared amplitudes for this thread's bins k = 1+tid+256j
  float a1v[8], a2v[8];
  #pragma unroll
  for (int j = 0; j < 8; ++j) {
    const int k = 1 + tid + (j << 8);
    if (k >= T / 2) { a1v[j] = -1e30f; a2v[j] = -1e30f; continue; }
    const float2 zk = Z[PAD(brev12(k))];
    const float2 zn = Z[PAD(brev12(T - k))];
    const float x1r = 0.5f * (zk.x + zn.x), x1i = 0.5f * (zk.y - zn.y);
    const float x2r = 0.5f * (zk.y + zn.y), x2i = 0.5f * (zn.x - zk.x);
    a1v[j] = x1r * x1r + x1i * x1i;
    a2v[j] = x2r * x2r + x2i * x2i;
  }

  // top-7 per real signal: local-max -> wave shuffle reduce -> 4-wave LDS reduce
  for (int sh = 0; sh < 2; ++sh) {
    for (int it = 0; it < TOPK; ++it) {
      float bv = -1e30f;
      int bj = 0;
      #pragma unroll
      for (int j = 0; j < 8; ++j) {
        const float v = (sh == 0) ? a1v[j] : a2v[j];
        if (v > bv) { bv = v; bj = j; }
      }
      int bk = 1 + tid + (bj << 8);
      #pragma unroll
      for (int off = 1; off < 64; off <<= 1) {
        const float ov = __shfl_xor(bv, off);
        const int   ok = __shfl_xor(bk, off);
        if (ov > bv) { bv = ov; bk = ok; }
      }
      if ((tid & 63) == 0) { s_rv[tid >> 6] = bv; s_rk[tid >> 6] = bk; }
      __syncthreads();
      float wv = s_rv[0];
      int   wk = s_rk[0];
      #pragma unroll
      for (int w = 1; w < 4; ++w)
        if (s_rv[w] > wv) { wv = s_rv[w]; wk = s_rk[w]; }
      // owning thread removes the winner from its registers
      if (((wk - 1) & 255) == tid) {
        const int j = (wk - 1) >> 8;
        #pragma unroll
        for (int jj = 0; jj < 8; ++jj)
          if (jj == j) { if (sh == 0) a1v[jj] = -1e30f; else a2v[jj] = -1e30f; }
      }
      if (tid == 0) {
        const float2 zk = Z[PAD(brev12(wk))];
        const float2 zn = Z[PAD(brev12(T - wk))];
        float re, im;
        if (sh == 0) { re = 0.5f * (zk.x + zn.x); im = 0.5f * (zk.y - zn.y); }
        else         { re = 0.5f * (zk.y + zn.y); im = 0.5f * (zn.x - zk.x); }
        s_cf[sh * TOPK + it] = make_float4((float)wk, re, im, 0.0f);
      }
      __syncthreads();
    }
  }

  // write 14 coeff float4s into this block's own xp region (all reads done)
  float4* cf = (float4*)g;
  if (tid < 2 * TOPK) cf[tid] = s_cf[tid];
}

// ---------------------------------------------------------------------------
// Kernel 3: direct sparse reconstruction, natural (b,t,d) layout, coalesced.
// out[b][t][d] = sum_j 2*(Re X_j cos(2pi k_j t/T) - Im X_j sin(2pi k_j t/T))
// via per-term rotation recurrence (no trans ops in the hot loop).
// ---------------------------------------------------------------------------
__global__ __launch_bounds__(256) void k_eval(const float* __restrict__ ws,
                                              float* __restrict__ out) {
  const int tx = threadIdx.x;          // 0..63 -> d offset
  const int ty = threadIdx.y;          // 0..3
  const int b  = blockIdx.z;
  const int d0 = blockIdx.y * 64;
  const int t0 = blockIdx.x * 256;
  const int d  = d0 + tx;
  const int P  = (b * D + d) >> 1;     // signal-pair id
  const int sh = d & 1;
  const float4* cf = (const float4*)(ws + (size_t)P * (2 * T)) + sh * TOPK;

  float re[TOPK], im[TOPK], cc[TOPK], ss[TOPK], cd[TOPK], sd[TOPK];
  const int ts = t0 + ty * 64;         // this thread's first t (64 consecutive)
  const float w0 = 6.283185307179586f / 4096.0f;
  #pragma unroll
  for (int j = 0; j < TOPK; ++j) {
    const float4 v = cf[j];
    const int k = (int)v.x;
    re[j] = 2.0f * v.y;
    im[j] = 2.0f * v.z;
    const int m0 = (k * ts) & (T - 1);
    __sincosf(w0 * (float)m0, &ss[j], &cc[j]);
    __sincosf(w0 * (float)k,  &sd[j], &cd[j]);
  }
  #pragma unroll 4
  for (int i = 0; i < 64; ++i) {
    float acc = 0.0f;
    #pragma unroll
    for (int j = 0; j < TOPK; ++j) {
      acc += re[j] * cc[j] - im[j] * ss[j];
      const float nc = cc[j] * cd[j] - ss[j] * sd[j];
      const float ns = ss[j] * cd[j] + cc[j] * sd[j];
      cc[j] = nc; ss[j] = ns;
    }
    out[((size_t)b * T + (ts + i)) * D + d] = acc;
  }
}

// ---------------------------------------------------------------------------
extern "C" void kernel_launch(void* const* d_in, const int* in_sizes, int n_in,
                              void* d_out, int out_size, void* d_ws, size_t ws_size,
                              hipStream_t stream) {
  const float* x = (const float*)d_in[0];
  float* out = (float*)d_out;
  float2* xp = (float2*)d_ws;   // 64 MB: (B, D/2, T) float2; coeffs overwrite it

  dim3 tgrid(T / 64, D / 64, B);
  dim3 tblock(64, 4, 1);
  hipLaunchKernelGGL(k_transpose_pack, tgrid, tblock, 0, stream, x, xp);
  hipLaunchKernelGGL(k_fft_topk, dim3(NPAIR), dim3(256), 0, stream, xp);
  dim3 egrid(T / 256, D / 64, B);
  hipLaunchKernelGGL(k_eval, egrid, tblock, 0, stream, (const float*)d_ws, out);
}

// Round 3
// 201.081 us; speedup vs baseline: 1.4543x; 1.0072x over previous
//
#include <hip/hip_runtime.h>
#include <math.h>

#define B 8
#define T 4096
#define D 512
#define NPAIR ((B * D) / 2)   // 2048 signal pairs
#define TOPK 7                // int(log(2047)) = 7
#define LOG2T 12
#define PAD(e) ((e) + ((e) >> 4))
#define ZSZ (T + (T >> 4))

__device__ __forceinline__ int brev12(int x) {
  return (int)(__brev((unsigned)x) >> (32 - LOG2T));
}

// ---------------------------------------------------------------------------
// Kernel 1: transpose + pack. x (B,T,D) f32 -> xp (B, D/2, T) float2
// float4 global loads along d; LDS tile stored transposed [d][t];
// float4 global stores along t (2 packed complex samples per store).
// ---------------------------------------------------------------------------
__global__ __launch_bounds__(256) void k_transpose_pack(const float* __restrict__ x,
                                                        float2* __restrict__ xp) {
  __shared__ float tT[64][65];     // [d][t]
  const int b  = blockIdx.z;
  const int t0 = blockIdx.x * 64;
  const int d0 = blockIdx.y * 64;
  const int tid = threadIdx.x;

  // load: 4 rows of 16 float4 per wave; scatter transposed into LDS
  const int c4 = tid & 15;         // float4 column in d
  const int r0 = tid >> 4;         // 0..15
  for (int r = r0; r < 64; r += 16) {
    const float4 v = *(const float4*)&x[((size_t)b * T + (t0 + r)) * D + d0 + 4 * c4];
    tT[4 * c4 + 0][r] = v.x;
    tT[4 * c4 + 1][r] = v.y;
    tT[4 * c4 + 2][r] = v.z;
    tT[4 * c4 + 3][r] = v.w;
  }
  __syncthreads();

  // pack + store: lanes along t, float4 = 2 consecutive complex samples
  const int tt  = tid & 31;        // t-pair index
  const int rp0 = tid >> 5;        // 0..7
  for (int rp = rp0; rp < 32; rp += 8) {
    const float2 a  = *(const float2*)&tT[2 * rp][2 * tt];       // (A_t, A_t+1)
    const float2 bb = *(const float2*)&tT[2 * rp + 1][2 * tt];   // (B_t, B_t+1)
    const float4 o = make_float4(a.x, bb.x, a.y, bb.y);
    *(float4*)&xp[((size_t)b * (D / 2) + (d0 / 2 + rp)) * T + t0 + 2 * tt] = o;
  }
}

// ---------------------------------------------------------------------------
// Kernel 2: forward FFT (radix-4 DIF, natural in -> bit-reversed out),
// register-resident amplitudes, top-7 per real signal, write 14 coeff float4s
// into this block's own (already consumed) xp region.  (unchanged)
// ---------------------------------------------------------------------------
__global__ __launch_bounds__(256) void k_fft_topk(float2* __restrict__ xp) {
  __shared__ float2 Z[ZSZ];          // ~34 KB, padded
  __shared__ float  s_rv[4];
  __shared__ int    s_rk[4];
  __shared__ float4 s_cf[2 * TOPK];

  const int tid = threadIdx.x;
  float2* g = xp + (size_t)blockIdx.x * T;

  for (int t = tid; t < T; t += 256) Z[PAD(t)] = g[t];
  __syncthreads();

  for (int s = 0; s < 6; ++s) {
    const int shift = 10 - 2 * s;
    const int q = 1 << shift;
    const float ang_scale = -6.283185307179586f / (float)(q << 2);
    for (int i = tid; i < T / 4; i += 256) {
      const int p    = i & (q - 1);
      const int base = ((i >> shift) << (shift + 2)) | p;
      float2 a0 = Z[PAD(base)];
      float2 a1 = Z[PAD(base + q)];
      float2 a2 = Z[PAD(base + 2 * q)];
      float2 a3 = Z[PAD(base + 3 * q)];
      float sw, cw;
      __sincosf(ang_scale * (float)p, &sw, &cw);
      const float c2 = cw * cw - sw * sw, s2 = 2.0f * cw * sw;
      const float c3 = c2 * cw - s2 * sw, s3 = c2 * sw + s2 * cw;
      const float t0r = a0.x + a2.x, t0i = a0.y + a2.y;
      const float t1r = a0.x - a2.x, t1i = a0.y - a2.y;
      const float t2r = a1.x + a3.x, t2i = a1.y + a3.y;
      const float t3r = a1.x - a3.x, t3i = a1.y - a3.y;
      Z[PAD(base)] = make_float2(t0r + t2r, t0i + t2i);
      const float u1r = t0r - t2r, u1i = t0i - t2i;
      Z[PAD(base + q)] = make_float2(u1r * c2 - u1i * s2, u1r * s2 + u1i * c2);
      const float u2r = t1r + t3i, u2i = t1i - t3r;
      Z[PAD(base + 2 * q)] = make_float2(u2r * cw - u2i * sw, u2r * sw + u2i * cw);
      const float u3r = t1r - t3i, u3i = t1i + t3r;
      Z[PAD(base + 3 * q)] = make_float2(u3r * c3 - u3i * s3, u3r * s3 + u3i * c3);
    }
    __syncthreads();
  }

  float a1v[8], a2v[8];
  #pragma unroll
  for (int j = 0; j < 8; ++j) {
    const int k = 1 + tid + (j << 8);
    if (k >= T / 2) { a1v[j] = -1e30f; a2v[j] = -1e30f; continue; }
    const float2 zk = Z[PAD(brev12(k))];
    const float2 zn = Z[PAD(brev12(T - k))];
    const float x1r = 0.5f * (zk.x + zn.x), x1i = 0.5f * (zk.y - zn.y);
    const float x2r = 0.5f * (zk.y + zn.y), x2i = 0.5f * (zn.x - zk.x);
    a1v[j] = x1r * x1r + x1i * x1i;
    a2v[j] = x2r * x2r + x2i * x2i;
  }

  for (int sh = 0; sh < 2; ++sh) {
    for (int it = 0; it < TOPK; ++it) {
      float bv = -1e30f;
      int bj = 0;
      #pragma unroll
      for (int j = 0; j < 8; ++j) {
        const float v = (sh == 0) ? a1v[j] : a2v[j];
        if (v > bv) { bv = v; bj = j; }
      }
      int bk = 1 + tid + (bj << 8);
      #pragma unroll
      for (int off = 1; off < 64; off <<= 1) {
        const float ov = __shfl_xor(bv, off);
        const int   ok = __shfl_xor(bk, off);
        if (ov > bv) { bv = ov; bk = ok; }
      }
      if ((tid & 63) == 0) { s_rv[tid >> 6] = bv; s_rk[tid >> 6] = bk; }
      __syncthreads();
      float wv = s_rv[0];
      int   wk = s_rk[0];
      #pragma unroll
      for (int w = 1; w < 4; ++w)
        if (s_rv[w] > wv) { wv = s_rv[w]; wk = s_rk[w]; }
      if (((wk - 1) & 255) == tid) {
        const int j = (wk - 1) >> 8;
        #pragma unroll
        for (int jj = 0; jj < 8; ++jj)
          if (jj == j) { if (sh == 0) a1v[jj] = -1e30f; else a2v[jj] = -1e30f; }
      }
      if (tid == 0) {
        const float2 zk = Z[PAD(brev12(wk))];
        const float2 zn = Z[PAD(brev12(T - wk))];
        float re, im;
        if (sh == 0) { re = 0.5f * (zk.x + zn.x); im = 0.5f * (zk.y - zn.y); }
        else         { re = 0.5f * (zk.y + zn.y); im = 0.5f * (zn.x - zk.x); }
        s_cf[sh * TOPK + it] = make_float4((float)wk, re, im, 0.0f);
      }
      __syncthreads();
    }
  }

  float4* cf = (float4*)g;
  if (tid < 2 * TOPK) cf[tid] = s_cf[tid];
}

// ---------------------------------------------------------------------------
// Kernel 3: direct sparse reconstruction.  64t x 64d tile per block.
// Lanes span d for compute (stride-4 rotation recurrence in t); results go
// through a 16 KB LDS tile so global stores are float4 along d.
// ---------------------------------------------------------------------------
__global__ __launch_bounds__(256) void k_eval(const float* __restrict__ ws,
                                              float* __restrict__ out) {
  __shared__ float  tile[64][64];        // [t_local][d_local], 16 KB
  __shared__ float4 s_coef[64 * TOPK];   // 7 KB: per-signal (k, re, im)

  const int tid = threadIdx.x;
  const int b   = blockIdx.z;
  const int d0  = blockIdx.y * 64;
  const int t0  = blockIdx.x * 64;

  // stage coefficients for this block's 64 signals into LDS
  for (int idx = tid; idx < 64 * TOPK; idx += 256) {
    const int s = idx / TOPK, j = idx - s * TOPK;
    const int P = (b * D + d0) / 2 + (s >> 1);
    const int sh = s & 1;
    s_coef[idx] = ((const float4*)(ws + (size_t)P * (2 * T)))[sh * TOPK + j];
  }
  __syncthreads();

  const int dl = tid & 63;               // d lane
  const int tg = tid >> 6;               // 0..3: t phase
  const float w0 = 6.283185307179586f / 4096.0f;

  float re[TOPK], im[TOPK], cc[TOPK], ss[TOPK], cd[TOPK], sd[TOPK];
  const int ts = t0 + tg;
  #pragma unroll
  for (int j = 0; j < TOPK; ++j) {
    const float4 v = s_coef[dl * TOPK + j];
    const int k = (int)v.x;
    re[j] = 2.0f * v.y;
    im[j] = 2.0f * v.z;
    const float a0 = w0 * (float)((k * ts) & (T - 1));
    const float ad = w0 * (float)((4 * k) & (T - 1));
    ss[j] = __sinf(a0); cc[j] = __cosf(a0);
    sd[j] = __sinf(ad); cd[j] = __cosf(ad);
  }

  #pragma unroll
  for (int i = 0; i < 16; ++i) {
    float acc = 0.0f;
    #pragma unroll
    for (int j = 0; j < TOPK; ++j) {
      acc += re[j] * cc[j] - im[j] * ss[j];
      const float nc = cc[j] * cd[j] - ss[j] * sd[j];
      const float ns = ss[j] * cd[j] + cc[j] * sd[j];
      cc[j] = nc; ss[j] = ns;
    }
    tile[tg + 4 * i][dl] = acc;
  }
  __syncthreads();

  // write out: float4 along d, 4 rows per wave
  const int c4 = tid & 15;
  const int rw = tid >> 4;               // 0..15
  for (int rr = rw; rr < 64; rr += 16) {
    const float4 v = *(const float4*)&tile[rr][4 * c4];
    *(float4*)&out[((size_t)b * T + (t0 + rr)) * D + d0 + 4 * c4] = v;
  }
}

// ---------------------------------------------------------------------------
extern "C" void kernel_launch(void* const* d_in, const int* in_sizes, int n_in,
                              void* d_out, int out_size, void* d_ws, size_t ws_size,
                              hipStream_t stream) {
  const float* x = (const float*)d_in[0];
  float* out = (float*)d_out;
  float2* xp = (float2*)d_ws;   // 64 MB: (B, D/2, T) float2; coeffs overwrite it

  dim3 tgrid(T / 64, D / 64, B);
  hipLaunchKernelGGL(k_transpose_pack, tgrid, dim3(256), 0, stream, x, xp);
  hipLaunchKernelGGL(k_fft_topk, dim3(NPAIR), dim3(256), 0, stream, xp);
  hipLaunchKernelGGL(k_eval, tgrid, dim3(256), 0, stream, (const float*)d_ws, out);
}

// Round 4
// 199.488 us; speedup vs baseline: 1.4659x; 1.0080x over previous
//
#include <hip/hip_runtime.h>
#include <math.h>

#define B 8
#define T 4096
#define D 512
#define NPAIR ((B * D) / 2)   // 2048 signal pairs
#define TOPK 7                // int(log(2047)) = 7
#define PAD(e) ((e) + ((e) >> 4))

// base-16 digit reverse of a 12-bit index (3 hex digits)
__device__ __forceinline__ int drev(int k) {
  return ((k & 15) << 8) | (k & 240) | (k >> 8);
}

__device__ __forceinline__ float2 cmul(float2 a, float2 b) {
  return make_float2(a.x * b.x - a.y * b.y, a.x * b.y + a.y * b.x);
}
__device__ __forceinline__ float2 cadd(float2 a, float2 b) { return make_float2(a.x + b.x, a.y + b.y); }
__device__ __forceinline__ float2 csub(float2 a, float2 b) { return make_float2(a.x - b.x, a.y - b.y); }
__device__ __forceinline__ float2 cmul_negi(float2 a) { return make_float2(a.y, -a.x); }  // a * (-i)

// forward 4-pt DFT, natural order, in place
__device__ __forceinline__ void dft4(float2& a, float2& b, float2& c, float2& d) {
  const float2 t0 = cadd(a, c), t1 = csub(a, c);
  const float2 t2 = cadd(b, d), t3n = cmul_negi(csub(b, d));   // -i*(b-d)
  a = cadd(t0, t2);
  b = cadd(t1, t3n);
  c = csub(t0, t2);
  d = csub(t1, t3n);
}

// forward 16-pt DFT in registers. Input natural order r[n].
// Output: X16[k] lands in r[SW4(k)], SW4(k) = ((k&3)<<2)|(k>>2).
#define C16 0.92387953251f
#define S16 0.38268343236f
#define RS2 0.70710678119f
__device__ __forceinline__ void dft16(float2 r[16]) {
  // inner: 4-pt over a1 for each a0 (stride 4); result u[a0][k0] at r[a0+4k0]
  dft4(r[0], r[4], r[8],  r[12]);
  dft4(r[1], r[5], r[9],  r[13]);
  dft4(r[2], r[6], r[10], r[14]);
  dft4(r[3], r[7], r[11], r[15]);
  // twiddles W16^(a0*k0) at slot a0+4k0
  const float2 W1 = make_float2(C16, -S16);
  const float2 W2 = make_float2(RS2, -RS2);
  const float2 W3 = make_float2(S16, -C16);
  const float2 W6 = make_float2(-RS2, -RS2);
  const float2 W9 = make_float2(-C16, S16);
  r[5]  = cmul(r[5],  W1);
  r[9]  = cmul(r[9],  W2);
  r[13] = cmul(r[13], W3);
  r[6]  = cmul(r[6],  W2);
  r[10] = cmul_negi(r[10]);        // W16^4 = -i
  r[14] = cmul(r[14], W6);
  r[7]  = cmul(r[7],  W3);
  r[11] = cmul(r[11], W6);
  r[15] = cmul(r[15], W9);
  // outer: 4-pt over a0 for each k0; X16[4k1+k0] at r[4k0+k1]
  dft4(r[0],  r[1],  r[2],  r[3]);
  dft4(r[4],  r[5],  r[6],  r[7]);
  dft4(r[8],  r[9],  r[10], r[11]);
  dft4(r[12], r[13], r[14], r[15]);
}
#define SW4(k) ((((k) & 3) << 2) | ((k) >> 2))

// ---------------------------------------------------------------------------
// Kernel 1: transpose + pack. x (B,T,D) f32 -> xp (B, D/2, T) float2  (unchanged)
// ---------------------------------------------------------------------------
__global__ __launch_bounds__(256) void k_transpose_pack(const float* __restrict__ x,
                                                        float2* __restrict__ xp) {
  __shared__ float tT[64][65];     // [d][t]
  const int b  = blockIdx.z;
  const int t0 = blockIdx.x * 64;
  const int d0 = blockIdx.y * 64;
  const int tid = threadIdx.x;

  const int c4 = tid & 15;
  const int r0 = tid >> 4;
  for (int r = r0; r < 64; r += 16) {
    const float4 v = *(const float4*)&x[((size_t)b * T + (t0 + r)) * D + d0 + 4 * c4];
    tT[4 * c4 + 0][r] = v.x;
    tT[4 * c4 + 1][r] = v.y;
    tT[4 * c4 + 2][r] = v.z;
    tT[4 * c4 + 3][r] = v.w;
  }
  __syncthreads();

  const int tt  = tid & 31;
  const int rp0 = tid >> 5;
  for (int rp = rp0; rp < 32; rp += 8) {
    const float2 a  = *(const float2*)&tT[2 * rp][2 * tt];
    const float2 bb = *(const float2*)&tT[2 * rp + 1][2 * tt];
    const float4 o = make_float4(a.x, bb.x, a.y, bb.y);
    *(float4*)&xp[((size_t)b * (D / 2) + (d0 / 2 + rp)) * T + t0 + 2 * tt] = o;
  }
}

// ---------------------------------------------------------------------------
// Kernel 2: register-resident 16x16x16 forward FFT (2 LDS exchanges),
// spectrum stored base-16 digit-reversed in LDS, then top-7 per real signal,
// 14 coeff float4s written into this block's own xp region.
// ---------------------------------------------------------------------------
__global__ __launch_bounds__(256) void k_fft_topk(float2* __restrict__ xp) {
  __shared__ float2 Z[PAD(T - 1) + 1];   // 4351 float2 ~ 34.8 KB
  __shared__ float  s_rv[2][4];
  __shared__ int    s_rk[2][4];
  __shared__ float4 s_cf[2 * TOPK];

  const int tid = threadIdx.x;
  float2* g = xp + (size_t)blockIdx.x * T;

  float2 r[16];
  // coalesced stride-256 loads straight into registers
  #pragma unroll
  for (int a = 0; a < 16; ++a) r[a] = g[(a << 8) + tid];

  // ---- stage A: DFT over high digit; twiddle W4096^(m*k1); scatter k1-major
  dft16(r);
  {
    float s, c;
    __sincosf(6.283185307179586f / 4096.0f * (float)tid, &s, &c);
    const float2 w = make_float2(c, -s);
    float2 t = make_float2(1.0f, 0.0f);
    Z[PAD(tid)] = r[0];
    #pragma unroll
    for (int k1 = 1; k1 < 16; ++k1) {
      t = cmul(t, w);
      Z[PAD((k1 << 8) + tid)] = cmul(r[SW4(k1)], t);
    }
  }
  __syncthreads();

  // ---- stage B: thread (k1, m1) = (tid>>4, tid&15); DFT over mid digit
  {
    const int m1 = tid & 15;
    const int base = ((tid >> 4) << 8) + m1;
    #pragma unroll
    for (int m2 = 0; m2 < 16; ++m2) r[m2] = Z[PAD(base + (m2 << 4))];
    dft16(r);
    float s, c;
    __sincosf(6.283185307179586f / 256.0f * (float)m1, &s, &c);
    const float2 w = make_float2(c, -s);
    float2 t = make_float2(1.0f, 0.0f);
    Z[PAD(base)] = r[0];                 // read-set == write-set: no barrier
    #pragma unroll
    for (int p = 1; p < 16; ++p) {
      t = cmul(t, w);
      Z[PAD(base + (p << 4))] = cmul(r[SW4(p)], t);
    }
  }
  __syncthreads();

  // ---- stage C: thread (k1, p); DFT over low digit; X[256q+16p+k1] -> e=base+q
  {
    const int base = tid << 4;           // 256*(tid>>4) + 16*(tid&15)
    #pragma unroll
    for (int m1 = 0; m1 < 16; ++m1) r[m1] = Z[PAD(base + m1)];
    dft16(r);
    #pragma unroll
    for (int q = 0; q < 16; ++q) Z[PAD(base + q)] = r[SW4(q)];
  }
  __syncthreads();

  // ---- register-resident squared amplitudes, bins k = 1+tid+256j
  float a1v[8], a2v[8];
  #pragma unroll
  for (int j = 0; j < 8; ++j) {
    const int k = 1 + tid + (j << 8);
    if (k >= T / 2) { a1v[j] = -1e30f; a2v[j] = -1e30f; continue; }
    const float2 zk = Z[PAD(drev(k))];
    const float2 zn = Z[PAD(drev(T - k))];
    const float x1r = 0.5f * (zk.x + zn.x), x1i = 0.5f * (zk.y - zn.y);
    const float x2r = 0.5f * (zk.y + zn.y), x2i = 0.5f * (zn.x - zk.x);
    a1v[j] = x1r * x1r + x1i * x1i;
    a2v[j] = x2r * x2r + x2i * x2i;
  }

  // ---- top-7 per real signal; lowest-k tie-break; double-buffered reduce
  for (int sh = 0; sh < 2; ++sh) {
    for (int it = 0; it < TOPK; ++it) {
      const int buf = (sh * TOPK + it) & 1;
      float bv = -1e30f;
      int bj = 0;
      #pragma unroll
      for (int j = 0; j < 8; ++j) {
        const float v = (sh == 0) ? a1v[j] : a2v[j];
        if (v > bv) { bv = v; bj = j; }
      }
      int bk = 1 + tid + (bj << 8);
      #pragma unroll
      for (int off = 1; off < 64; off <<= 1) {
        const float ov = __shfl_xor(bv, off);
        const int   ok = __shfl_xor(bk, off);
        if (ov > bv || (ov == bv && ok < bk)) { bv = ov; bk = ok; }
      }
      if ((tid & 63) == 0) { s_rv[buf][tid >> 6] = bv; s_rk[buf][tid >> 6] = bk; }
      __syncthreads();
      float wv = s_rv[buf][0];
      int   wk = s_rk[buf][0];
      #pragma unroll
      for (int w = 1; w < 4; ++w) {
        const float ov = s_rv[buf][w];
        const int   ok = s_rk[buf][w];
        if (ov > wv || (ov == wv && ok < wk)) { wv = ov; wk = ok; }
      }
      if (((wk - 1) & 255) == tid) {
        const int j = (wk - 1) >> 8;
        #pragma unroll
        for (int jj = 0; jj < 8; ++jj)
          if (jj == j) { if (sh == 0) a1v[jj] = -1e30f; else a2v[jj] = -1e30f; }
      }
      if (tid == 0) {
        const float2 zk = Z[PAD(drev(wk))];
        const float2 zn = Z[PAD(drev(T - wk))];
        float re, im;
        if (sh == 0) { re = 0.5f * (zk.x + zn.x); im = 0.5f * (zk.y - zn.y); }
        else         { re = 0.5f * (zk.y + zn.y); im = 0.5f * (zn.x - zk.x); }
        s_cf[sh * TOPK + it] = make_float4((float)wk, re, im, 0.0f);
      }
    }
  }
  __syncthreads();

  float4* cf = (float4*)g;
  if (tid < 2 * TOPK) cf[tid] = s_cf[tid];
}

// ---------------------------------------------------------------------------
// Kernel 3: direct sparse reconstruction, 64t x 64d tile per block (unchanged)
// ---------------------------------------------------------------------------
__global__ __launch_bounds__(256) void k_eval(const float* __restrict__ ws,
                                              float* __restrict__ out) {
  __shared__ float  tile[64][64];
  __shared__ float4 s_coef[64 * TOPK];

  const int tid = threadIdx.x;
  const int b   = blockIdx.z;
  const int d0  = blockIdx.y * 64;
  const int t0  = blockIdx.x * 64;

  for (int idx = tid; idx < 64 * TOPK; idx += 256) {
    const int s = idx / TOPK, j = idx - s * TOPK;
    const int P = (b * D + d0) / 2 + (s >> 1);
    const int sh = s & 1;
    s_coef[idx] = ((const float4*)(ws + (size_t)P * (2 * T)))[sh * TOPK + j];
  }
  __syncthreads();

  const int dl = tid & 63;
  const int tg = tid >> 6;
  const float w0 = 6.283185307179586f / 4096.0f;

  float re[TOPK], im[TOPK], cc[TOPK], ss[TOPK], cd[TOPK], sd[TOPK];
  const int ts = t0 + tg;
  #pragma unroll
  for (int j = 0; j < TOPK; ++j) {
    const float4 v = s_coef[dl * TOPK + j];
    const int k = (int)v.x;
    re[j] = 2.0f * v.y;
    im[j] = 2.0f * v.z;
    const float a0 = w0 * (float)((k * ts) & (T - 1));
    const float ad = w0 * (float)((4 * k) & (T - 1));
    ss[j] = __sinf(a0); cc[j] = __cosf(a0);
    sd[j] = __sinf(ad); cd[j] = __cosf(ad);
  }

  #pragma unroll
  for (int i = 0; i < 16; ++i) {
    float acc = 0.0f;
    #pragma unroll
    for (int j = 0; j < TOPK; ++j) {
      acc += re[j] * cc[j] - im[j] * ss[j];
      const float nc = cc[j] * cd[j] - ss[j] * sd[j];
      const float ns = ss[j] * cd[j] + cc[j] * sd[j];
      cc[j] = nc; ss[j] = ns;
    }
    tile[tg + 4 * i][dl] = acc;
  }
  __syncthreads();

  const int c4 = tid & 15;
  const int rw = tid >> 4;
  for (int rr = rw; rr < 64; rr += 16) {
    const float4 v = *(const float4*)&tile[rr][4 * c4];
    *(float4*)&out[((size_t)b * T + (t0 + rr)) * D + d0 + 4 * c4] = v;
  }
}

// ---------------------------------------------------------------------------
extern "C" void kernel_launch(void* const* d_in, const int* in_sizes, int n_in,
                              void* d_out, int out_size, void* d_ws, size_t ws_size,
                              hipStream_t stream) {
  const float* x = (const float*)d_in[0];
  float* out = (float*)d_out;
  float2* xp = (float2*)d_ws;

  dim3 tgrid(T / 64, D / 64, B);
  hipLaunchKernelGGL(k_transpose_pack, tgrid, dim3(256), 0, stream, x, xp);
  hipLaunchKernelGGL(k_fft_topk, dim3(NPAIR), dim3(256), 0, stream, xp);
  hipLaunchKernelGGL(k_eval, tgrid, dim3(256), 0, stream, (const float*)d_ws, out);
}